// Round 4
// baseline (401.242 us; speedup 1.0000x reference)
//
#include <hip/hip_runtime.h>
#include <cstddef>

#define TSTEPS 1024
#define NIN    49
#define HID    32
#define OUTD   10
#define XSTR   52          // x row stride in LDS floats
#define NGRP   256         // 256 groups of 4 timesteps

typedef float v2f __attribute__((ext_vector_type(2)));

// force true register residency: value becomes opaque -> not rematerializable,
// allocator must keep it in a VGPR (emits zero instructions)
#define PINF(v) asm volatile("" : "+v"(v))

template<int CTRL>
__device__ __forceinline__ float quad(float v) {
    return __int_as_float(__builtin_amdgcn_mov_dpp(__float_as_int(v), CTRL, 0xF, 0xF, true));
}
__device__ __forceinline__ float sigm(float x) {
    return __builtin_amdgcn_rcpf(1.f + __expf(-x));
}
// dual fp32 FMA: acc.xy += a.xy * b.xy   (VOP3P, one issue slot)
__device__ __forceinline__ void pkfma(v2f& acc, v2f a, v2f b) {
    asm("v_pk_fma_f32 %0, %1, %2, %0" : "+v"(acc) : "v"(a), "v"(b));
}

// ---- barrier-free flow control: monotonic LDS counters -------------------
__device__ __forceinline__ int ldacq(const int* p) {
    return __hip_atomic_load(p, __ATOMIC_ACQUIRE, __HIP_MEMORY_SCOPE_WORKGROUP);
}
__device__ __forceinline__ void pub(int* p, int v, int lane) {
    if (lane == 0)
        __hip_atomic_store(p, v, __ATOMIC_RELEASE, __HIP_MEMORY_SCOPE_WORKGROUP);
}
__device__ __forceinline__ void waitge(const int* p, int need, int& cache) {
    if (cache >= need) return;
    int c = ldacq(p);
    while (c < need) { __builtin_amdgcn_s_sleep(1); c = ldacq(p); }
    cache = c;
}

// read 16 floats as 8 float2 pairs via 4x ds_read_b128
#define LOADH2(BASE, H2)                                                     \
    v2f H2[8];                                                               \
    {                                                                        \
        const float4* hp_ = (const float4*)(BASE);                           \
        const float4 a_ = hp_[0], b_ = hp_[1], c_ = hp_[2], d_ = hp_[3];     \
        H2[0] = (v2f){a_.x, a_.y}; H2[1] = (v2f){a_.z, a_.w};                \
        H2[2] = (v2f){b_.x, b_.y}; H2[3] = (v2f){b_.z, b_.w};                \
        H2[4] = (v2f){c_.x, c_.y}; H2[5] = (v2f){c_.z, c_.w};                \
        H2[6] = (v2f){d_.x, d_.y}; H2[7] = (v2f){d_.z, d_.w};                \
    }

// 4 gates x 16-elem half-dot via v_pk_fma_f32 (32 instrs), quad-pair combine
#define DOTPK(W2, H2, S0, S1, S2, S3)                                        \
    float S0, S1, S2, S3;                                                    \
    {                                                                        \
        v2f p0 = {0.f,0.f}, p1 = {0.f,0.f}, p2 = {0.f,0.f}, p3 = {0.f,0.f}; \
        _Pragma("unroll")                                                    \
        for (int m_ = 0; m_ < 8; ++m_) {                                     \
            pkfma(p0, W2[0][m_], H2[m_]);                                    \
            pkfma(p1, W2[1][m_], H2[m_]);                                    \
            pkfma(p2, W2[2][m_], H2[m_]);                                    \
            pkfma(p3, W2[3][m_], H2[m_]);                                    \
        }                                                                    \
        S0 = p0.x + p0.y; S1 = p1.x + p1.y;                                  \
        S2 = p2.x + p2.y; S3 = p3.x + p3.y;                                  \
        S0 += quad<0xB1>(S0); S1 += quad<0xB1>(S1);                          \
        S2 += quad<0xB1>(S2); S3 += quad<0xB1>(S3);                          \
    }

// gates (i,f,g,o) -> c,h; transcendental split across the lane pair
__device__ __forceinline__ float gate_act(float s0, float s1, float s2, float s3,
                                          int gp, float& c) {
    const float inA = gp ? s2 + s2 : s0;
    const float inB = gp ? s3 : s1;
    const float sA = sigm(inA);                      // gp0: sig(i)   gp1: sig(2g)
    const float sB = sigm(inB);                      // gp0: sig(f)   gp1: sig(o)
    const float vA = gp ? fmaf(2.f, sA, -1.f) : sA;  // gp0: i_act    gp1: tanh(g)
    const float xA = quad<0xB1>(vA);
    const float xB = quad<0xB1>(sB);
    const float ig = gp ? xA : vA;
    const float fg = gp ? xB : sB;
    const float gg = gp ? vA : xA;
    const float og = gp ? sB : xB;
    c = fmaf(fg, c, ig * gg);
    return og * fmaf(2.f, sigm(c + c), -1.f);        // tanh(c) = 2*sig(2c)-1
}

extern "C" __global__ void __launch_bounds__(256, 2)
lstm_pin(const float* __restrict__ x,
         const float* __restrict__ Wih0, const float* __restrict__ Whh0,
         const float* __restrict__ bih0, const float* __restrict__ bhh0,
         const float* __restrict__ Wih1, const float* __restrict__ Whh1,
         const float* __restrict__ bih1, const float* __restrict__ bhh1,
         const float* __restrict__ Wout, const float* __restrict__ bout,
         float* __restrict__ y)
{
    const int tid  = threadIdx.x;   // 0..255 = 4 waves, one role each
    const int wv   = tid >> 6;      // 0:L0  1:qdot+proj  2:L1  3:producer
    const int lane = tid & 63;

    __shared__ __align__(16) float xs[2 * 16 * XSTR];   // x chunks (producer-private)
    __shared__ __align__(16) float xg0[16][HID][4];     // Wih0*x + b0 ring
    __shared__ __align__(16) float xg1[16][HID][4];     // Wih1*h0 + b1 ring
    __shared__ __align__(16) float h0r[16][HID];        // h0 ring
    __shared__ __align__(16) float h1r[16][HID];        // h1 ring
    __shared__ int ctr[5];   // 0:prod 1:l0 2:qd 3:l1 4:prj  (valid through step v)

    {   // zero h rings (slot 15 is h[-1] = 0) + counters
        float* z0 = &h0r[0][0];
        float* z1 = &h1r[0][0];
        for (int i = tid; i < 16 * HID; i += 256) { z0[i] = 0.f; z1[i] = 0.f; }
        if (tid < 5) ctr[tid] = -1;
    }
    __syncthreads();   // the only barrier in the kernel

    const float* __restrict__ xb = x + (size_t)blockIdx.x * TSTEPS * NIN;
    float* __restrict__ yb       = y + (size_t)blockIdx.x * TSTEPS * OUTD;

    if (wv == 0) {
        // ===================== L0 recurrence: steps 4g..4g+3 =====================
        const int j = lane >> 1, gp = lane & 1;
        v2f wh0[4][8];
#pragma unroll
        for (int g = 0; g < 4; ++g) {
            const float* wr = Whh0 + (g * HID + j) * HID + 16 * gp;
#pragma unroll
            for (int m = 0; m < 8; ++m) wh0[g][m] = (v2f){wr[2*m], wr[2*m + 1]};
        }
#pragma unroll
        for (int g = 0; g < 4; ++g)
#pragma unroll
            for (int m = 0; m < 8; ++m) PINF(wh0[g][m]);

        float c0 = 0.f;
        int cProd = -1, cQd = -1;
        __builtin_amdgcn_s_setprio(1);   // chain wave
        for (int g = 0; g < NGRP; ++g) {
            waitge(&ctr[0], 4 * g + 3, cProd);          // xg0[4g..4g+3] ready
            if (g >= 4) waitge(&ctr[2], 4 * g - 13, cQd);  // h0 ring slots free
#pragma unroll
            for (int u = 0; u < 4; ++u) {
                const int t = 4 * g + u;
                LOADH2(&h0r[(t + 15) & 15][16 * gp], hv)
                DOTPK(wh0, hv, s0, s1, s2, s3)
                const float4 xg = *(const float4*)&xg0[t & 15][j][0];
                const float hval = gate_act(s0 + xg.x, s1 + xg.y,
                                            s2 + xg.z, s3 + xg.w, gp, c0);
                if (gp == 0) h0r[t & 15][j] = hval;
            }
            pub(&ctr[1], 4 * g + 3, lane);
        }
    } else if (wv == 1) {
        // ============ qdot: xg1[4g..4g+3]; deferred proj: y[4(g-2)..] ============
        const int j = lane >> 1, gp = lane & 1;
        v2f wi1[4][8];
        float b1v[4];
#pragma unroll
        for (int g = 0; g < 4; ++g) {
            const float* wr = Wih1 + (g * HID + j) * HID + 16 * gp;
#pragma unroll
            for (int m = 0; m < 8; ++m) wi1[g][m] = (v2f){wr[2*m], wr[2*m + 1]};
            b1v[g] = bih1[g * HID + j] + bhh1[g * HID + j];
        }
        // projection state (lanes 0..39): po = lane>>2, kq = lane&3
        float wo[8], bo = 0.f;
        const int po = lane >> 2, kq = lane & 3;
        if (lane < 40) {
#pragma unroll
            for (int m = 0; m < 8; ++m) wo[m] = Wout[po * HID + kq * 8 + m];
            bo = bout[po];
        } else {
#pragma unroll
            for (int m = 0; m < 8; ++m) wo[m] = 0.f;
        }
#pragma unroll
        for (int g = 0; g < 4; ++g) {
#pragma unroll
            for (int m = 0; m < 8; ++m) PINF(wi1[g][m]);
            PINF(b1v[g]);
        }
#pragma unroll
        for (int m = 0; m < 8; ++m) PINF(wo[m]);
        PINF(bo);

        int cL0 = -1, cL1b = -1, cL1d = -1;
        for (int g = 0; g < NGRP + 2; ++g) {
            if (g < NGRP) {
                waitge(&ctr[1], 4 * g + 3, cL0);           // h0[4g..4g+3] ready
                if (g >= 4) waitge(&ctr[3], 4 * g - 13, cL1b);  // xg1 slots free
#pragma unroll
                for (int u = 0; u < 4; ++u) {
                    const int t = 4 * g + u;
                    LOADH2(&h0r[t & 15][16 * gp], hq)
                    DOTPK(wi1, hq, q0, q1, q2, q3)
                    if (gp == 0) {
                        float4 o;
                        o.x = q0 + b1v[0]; o.y = q1 + b1v[1];
                        o.z = q2 + b1v[2]; o.w = q3 + b1v[3];
                        *(float4*)&xg1[t & 15][j][0] = o;
                    }
                }
                pub(&ctr[2], 4 * g + 3, lane);
            }
            if (g >= 2) {
                const int gy = g - 2;
                waitge(&ctr[3], 4 * gy + 3, cL1d);         // h1[4gy..4gy+3] ready
#pragma unroll
                for (int u = 0; u < 4; ++u) {
                    const int ty = 4 * gy + u;
                    const float* hb = &h1r[ty & 15][kq * 8];
                    const float4 va = *(const float4*)hb;
                    const float4 vb = *(const float4*)(hb + 4);
                    float acc = wo[0]*va.x + wo[1]*va.y + wo[2]*va.z + wo[3]*va.w
                              + wo[4]*vb.x + wo[5]*vb.y + wo[6]*vb.z + wo[7]*vb.w;
                    acc += quad<0xB1>(acc);
                    acc += quad<0x4E>(acc);
                    if (lane < 40 && kq == 0) yb[(size_t)ty * OUTD + po] = acc + bo;
                }
                pub(&ctr[4], 4 * gy + 3, lane);
            }
        }
    } else if (wv == 2) {
        // ===================== L1 recurrence: steps 4g..4g+3 =====================
        const int j = lane >> 1, gp = lane & 1;
        v2f wh1[4][8];
#pragma unroll
        for (int g = 0; g < 4; ++g) {
            const float* wr = Whh1 + (g * HID + j) * HID + 16 * gp;
#pragma unroll
            for (int m = 0; m < 8; ++m) wh1[g][m] = (v2f){wr[2*m], wr[2*m + 1]};
        }
#pragma unroll
        for (int g = 0; g < 4; ++g)
#pragma unroll
            for (int m = 0; m < 8; ++m) PINF(wh1[g][m]);

        float c1 = 0.f;
        int cQd = -1, cPrj = -1;
        __builtin_amdgcn_s_setprio(1);   // chain wave
        for (int g = 0; g < NGRP; ++g) {
            waitge(&ctr[2], 4 * g + 3, cQd);               // xg1[4g..4g+3] ready
            if (g >= 4) waitge(&ctr[4], 4 * g - 13, cPrj); // h1 ring slots free
#pragma unroll
            for (int u = 0; u < 4; ++u) {
                const int t = 4 * g + u;
                LOADH2(&h1r[(t + 15) & 15][16 * gp], hv)
                DOTPK(wh1, hv, s0, s1, s2, s3)
                const float4 xg = *(const float4*)&xg1[t & 15][j][0];
                const float hval = gate_act(s0 + xg.x, s1 + xg.y,
                                            s2 + xg.z, s3 + xg.w, gp, c1);
                if (gp == 0) h1r[t & 15][j] = hval;
            }
            pub(&ctr[3], 4 * g + 3, lane);
        }
    } else {
        // ============ producer: xg0[4g..4g+3] = Wih0*x + b0; x staging ============
        // lane owns 2 gate-rows: (gA=lane>>5, jj) and (gB=gA+2, jj).
        const int jj = lane & 31;
        const int gA = lane >> 5;        // 0..1
        const int gB = 2 + (lane >> 5);  // 2..3

        v2f wa2[24], wb2[24];
        float wa48, wb48, b0a, b0b;
        {
            const float* wra = Wih0 + (gA * HID + jj) * NIN;
            const float* wrb = Wih0 + (gB * HID + jj) * NIN;
#pragma unroll
            for (int m = 0; m < 24; ++m) {
                wa2[m] = (v2f){wra[2*m], wra[2*m + 1]};
                wb2[m] = (v2f){wrb[2*m], wrb[2*m + 1]};
            }
            wa48 = wra[48]; wb48 = wrb[48];
            b0a = bih0[gA * HID + jj] + bhh0[gA * HID + jj];
            b0b = bih0[gB * HID + jj] + bhh0[gB * HID + jj];
        }
        // pin the full 96-VGPR weight set resident (this branch was being
        // register-rationed to 84 VGPRs -> per-iteration global reloads)
#pragma unroll
        for (int m = 0; m < 24; ++m) { PINF(wa2[m]); PINF(wb2[m]); }
        PINF(wa48); PINF(wb48); PINF(b0a); PINF(b0b);

        int laddr[13];
#pragma unroll
        for (int r = 0; r < 13; ++r) {
            const int idx = lane + r * 64;
            const int s_  = idx / NIN;
            laddr[r] = s_ * XSTR + (idx - s_ * NIN);
        }
        float xr[13];

        auto issue = [&](int cn) {
            const float* src = xb + (size_t)cn * 16 * NIN;
#pragma unroll
            for (int r = 0; r < 12; ++r) xr[r] = src[lane + r * 64];
            if (lane < 16) xr[12] = src[lane + 768];
        };
        auto drain = [&](int cn) {
            float* dst = &xs[(cn & 1) * (16 * XSTR)];
#pragma unroll
            for (int r = 0; r < 12; ++r) dst[laddr[r]] = xr[r];
            if (lane < 16) dst[laddr[12]] = xr[12];
        };
        auto pdot = [&](int t) {
            const float* xp = &xs[((t >> 4) & 1) * (16 * XSTR) + (t & 15) * XSTR];
            const float4* x4 = (const float4*)xp;   // wave-uniform broadcast reads
            v2f aA0 = (v2f){b0a, 0.f}, aA1 = (v2f){0.f, 0.f};
            v2f aB0 = (v2f){b0b, 0.f}, aB1 = (v2f){0.f, 0.f};
#pragma unroll
            for (int u = 0; u < 12; ++u) {
                const float4 xv = x4[u];
                const v2f xlo = (v2f){xv.x, xv.y};
                const v2f xhi = (v2f){xv.z, xv.w};
                pkfma(aA0, wa2[2*u],     xlo);
                pkfma(aA1, wa2[2*u + 1], xhi);
                pkfma(aB0, wb2[2*u],     xlo);
                pkfma(aB1, wb2[2*u + 1], xhi);
            }
            const float x48 = xp[48];
            const float a0 = fmaf(wa48, x48, (aA0.x + aA0.y) + (aA1.x + aA1.y));
            const float a2 = fmaf(wb48, x48, (aB0.x + aB0.y) + (aB1.x + aB1.y));
            xg0[t & 15][jj][gA] = a0;
            xg0[t & 15][jj][gB] = a2;
        };

        // prologue: stage chunk 0 (xs is producer-private; in-wave lgkmcnt orders it)
        issue(0);
        drain(0);

        int cL0 = -1;
        for (int g = 0; g < NGRP; ++g) {
            if (g >= 4) waitge(&ctr[1], 4 * g - 13, cL0);   // xg0 ring slots free
            const int cn = (g >> 2) + 1;
            if ((g & 3) == 0 && cn < 64) issue(cn);
            pdot(4 * g); pdot(4 * g + 1); pdot(4 * g + 2); pdot(4 * g + 3);
            if ((g & 3) == 2 && cn < 64) drain(cn);
            pub(&ctr[0], 4 * g + 3, lane);
        }
    }
}

extern "C" void kernel_launch(void* const* d_in, const int* in_sizes, int n_in,
                              void* d_out, int out_size, void* d_ws, size_t ws_size,
                              hipStream_t stream) {
    (void)in_sizes; (void)n_in; (void)d_ws; (void)ws_size; (void)out_size;
    const float* x    = (const float*)d_in[0];
    const float* Wih0 = (const float*)d_in[1];
    const float* Whh0 = (const float*)d_in[2];
    const float* bih0 = (const float*)d_in[3];
    const float* bhh0 = (const float*)d_in[4];
    const float* Wih1 = (const float*)d_in[5];
    const float* Whh1 = (const float*)d_in[6];
    const float* bih1 = (const float*)d_in[7];
    const float* bhh1 = (const float*)d_in[8];
    const float* Wout = (const float*)d_in[9];
    const float* bout = (const float*)d_in[10];
    float* y = (float*)d_out;

    lstm_pin<<<dim3(512), dim3(256), 0, stream>>>(
        x, Wih0, Whh0, bih0, bhh0, Wih1, Whh1, bih1, bhh1, Wout, bout, y);
}

// Round 5
// 395.548 us; speedup vs baseline: 1.0144x; 1.0144x over previous
//
#include <hip/hip_runtime.h>
#include <cstddef>

#define TSTEPS 1024
#define NIN    49
#define HID    32
#define OUTD   10
#define XSTR   52          // x row stride in LDS floats
#define NGRP   256         // 256 groups of 4 timesteps
#define RMASK  31          // 32-slot rings (8 groups of slack)

typedef float v2f __attribute__((ext_vector_type(2)));

template<int CTRL>
__device__ __forceinline__ float quad(float v) {
    return __int_as_float(__builtin_amdgcn_mov_dpp(__float_as_int(v), CTRL, 0xF, 0xF, true));
}
__device__ __forceinline__ float sigm(float x) {
    return __builtin_amdgcn_rcpf(1.f + __expf(-x));
}
// dual fp32 FMA: acc.xy += a.xy * b.xy   (VOP3P, one issue slot)
__device__ __forceinline__ void pkfma(v2f& acc, v2f a, v2f b) {
    asm("v_pk_fma_f32 %0, %1, %2, %0" : "+v"(acc) : "v"(a), "v"(b));
}

// ---- barrier-free flow control: monotonic LDS counters -------------------
__device__ __forceinline__ int ldacq(const int* p) {
    return __hip_atomic_load(p, __ATOMIC_ACQUIRE, __HIP_MEMORY_SCOPE_WORKGROUP);
}
__device__ __forceinline__ void pub(int* p, int v, int lane) {
    if (lane == 0)
        __hip_atomic_store(p, v, __ATOMIC_RELEASE, __HIP_MEMORY_SCOPE_WORKGROUP);
}
__device__ __forceinline__ void waitge(const int* p, int need, int& cache) {
    if (cache >= need) return;
    int c = ldacq(p);
    while (c < need) { __builtin_amdgcn_s_sleep(1); c = ldacq(p); }
    cache = c;
}

// read 16 floats as 8 float2 pairs via 4x ds_read_b128
#define LOADH2(BASE, H2)                                                     \
    v2f H2[8];                                                               \
    {                                                                        \
        const float4* hp_ = (const float4*)(BASE);                           \
        const float4 a_ = hp_[0], b_ = hp_[1], c_ = hp_[2], d_ = hp_[3];     \
        H2[0] = (v2f){a_.x, a_.y}; H2[1] = (v2f){a_.z, a_.w};                \
        H2[2] = (v2f){b_.x, b_.y}; H2[3] = (v2f){b_.z, b_.w};                \
        H2[4] = (v2f){c_.x, c_.y}; H2[5] = (v2f){c_.z, c_.w};                \
        H2[6] = (v2f){d_.x, d_.y}; H2[7] = (v2f){d_.z, d_.w};                \
    }

// 4 gates x 16-elem half-dot via v_pk_fma_f32 (32 instrs), quad-pair combine
#define DOTPK(W2, H2, S0, S1, S2, S3)                                        \
    float S0, S1, S2, S3;                                                    \
    {                                                                        \
        v2f p0 = {0.f,0.f}, p1 = {0.f,0.f}, p2 = {0.f,0.f}, p3 = {0.f,0.f}; \
        _Pragma("unroll")                                                    \
        for (int m_ = 0; m_ < 8; ++m_) {                                     \
            pkfma(p0, W2[0][m_], H2[m_]);                                    \
            pkfma(p1, W2[1][m_], H2[m_]);                                    \
            pkfma(p2, W2[2][m_], H2[m_]);                                    \
            pkfma(p3, W2[3][m_], H2[m_]);                                    \
        }                                                                    \
        S0 = p0.x + p0.y; S1 = p1.x + p1.y;                                  \
        S2 = p2.x + p2.y; S3 = p3.x + p3.y;                                  \
        S0 += quad<0xB1>(S0); S1 += quad<0xB1>(S1);                          \
        S2 += quad<0xB1>(S2); S3 += quad<0xB1>(S3);                          \
    }

// gates (i,f,g,o) -> c,h; transcendental split across the lane pair.
// Folded: ig*gg == vA*xA in BOTH parities (fp mul commutes bitwise),
// so only fg/og need parity selects. Bit-identical to the original.
__device__ __forceinline__ float gate_act(float s0, float s1, float s2, float s3,
                                          int gp, float& c) {
    const float inA = gp ? s2 + s2 : s0;
    const float inB = gp ? s3 : s1;
    const float sA = sigm(inA);                      // gp0: sig(i)   gp1: sig(2g)
    const float sB = sigm(inB);                      // gp0: sig(f)   gp1: sig(o)
    const float vA = gp ? fmaf(2.f, sA, -1.f) : sA;  // gp0: i_act    gp1: tanh(g)
    const float xA = quad<0xB1>(vA);
    const float xB = quad<0xB1>(sB);
    const float fg = gp ? xB : sB;
    const float og = gp ? sB : xB;
    c = fmaf(fg, c, vA * xA);
    return og * fmaf(2.f, sigm(c + c), -1.f);        // tanh(c) = 2*sig(2c)-1
}

extern "C" __global__ void __launch_bounds__(256, 2)
lstm_amort(const float* __restrict__ x,
           const float* __restrict__ Wih0, const float* __restrict__ Whh0,
           const float* __restrict__ bih0, const float* __restrict__ bhh0,
           const float* __restrict__ Wih1, const float* __restrict__ Whh1,
           const float* __restrict__ bih1, const float* __restrict__ bhh1,
           const float* __restrict__ Wout, const float* __restrict__ bout,
           float* __restrict__ y)
{
    const int tid  = threadIdx.x;   // 0..255 = 4 waves, one role each
    const int lane = tid & 63;
    // Heavy+light SIMD pairing: co-resident blocks (differing in bit 0 or bit 8)
    // get role maps XOR'd, so a SIMD hosts {L0 + qdot} / {L1 + producer}
    // instead of two copies of the same role. Wrong co-residency guess = no-op.
    const int p    = (blockIdx.x ^ (blockIdx.x >> 8)) & 1;
    const int role = (tid >> 6) ^ p;   // 0:L0  1:qdot+proj  2:L1  3:producer

    __shared__ __align__(16) float xs[2 * 16 * XSTR];   // x chunks (producer-private)
    __shared__ __align__(16) float xg0[32][HID][4];     // Wih0*x + b0 ring (32 slots)
    __shared__ __align__(16) float xg1[32][HID][4];     // Wih1*h0 + b1 ring
    __shared__ __align__(16) float h0r[32][HID];        // h0 ring
    __shared__ __align__(16) float h1r[32][HID];        // h1 ring
    __shared__ int ctr[5];   // 0:prod 1:l0 2:qd 3:l1 4:prj  (valid through step v)

    {   // zero h rings (slot 31 is h[-1] = 0) + counters
        float* z0 = &h0r[0][0];
        float* z1 = &h1r[0][0];
        for (int i = tid; i < 32 * HID; i += 256) { z0[i] = 0.f; z1[i] = 0.f; }
        if (tid < 5) ctr[tid] = -1;
    }
    __syncthreads();   // the only barrier in the kernel

    const float* __restrict__ xb = x + (size_t)blockIdx.x * TSTEPS * NIN;
    float* __restrict__ yb       = y + (size_t)blockIdx.x * TSTEPS * OUTD;

    if (role == 0) {
        // ===================== L0 recurrence: steps 4g..4g+3 =====================
        const int j = lane >> 1, gp = lane & 1;
        v2f wh0[4][8];
#pragma unroll
        for (int g = 0; g < 4; ++g) {
            const float* wr = Whh0 + (g * HID + j) * HID + 16 * gp;
#pragma unroll
            for (int m = 0; m < 8; ++m) wh0[g][m] = (v2f){wr[2*m], wr[2*m + 1]};
        }
        float c0 = 0.f;
        int cProd = -1, cQd = -1;
        __builtin_amdgcn_s_setprio(1);   // chain wave
        for (int g = 0; g < NGRP; ++g) {
            if ((g & 3) == 0) {          // super-group boundary: amortized polls
                waitge(&ctr[0], 4 * g + 15, cProd);            // xg0 for 16 steps
                if (g >= 8) waitge(&ctr[2], 4 * g - 17, cQd);  // h0 ring slots free
            }
#pragma unroll
            for (int u = 0; u < 4; ++u) {
                const int t = 4 * g + u;
                LOADH2(&h0r[(t + RMASK) & RMASK][16 * gp], hv)
                DOTPK(wh0, hv, s0, s1, s2, s3)
                const float4 xg = *(const float4*)&xg0[t & RMASK][j][0];
                const float hval = gate_act(s0 + xg.x, s1 + xg.y,
                                            s2 + xg.z, s3 + xg.w, gp, c0);
                if (gp == 0) h0r[t & RMASK][j] = hval;
            }
            pub(&ctr[1], 4 * g + 3, lane);
        }
    } else if (role == 1) {
        // ============ qdot: xg1[4g..4g+3]; deferred proj: y[4(g-8)..] ============
        const int j = lane >> 1, gp = lane & 1;
        v2f wi1[4][8];
        float b1v[4];
#pragma unroll
        for (int g = 0; g < 4; ++g) {
            const float* wr = Wih1 + (g * HID + j) * HID + 16 * gp;
#pragma unroll
            for (int m = 0; m < 8; ++m) wi1[g][m] = (v2f){wr[2*m], wr[2*m + 1]};
            b1v[g] = bih1[g * HID + j] + bhh1[g * HID + j];
        }
        // projection state (lanes 0..39): po = lane>>2, kq = lane&3
        float wo[8], bo = 0.f;
        const int po = lane >> 2, kq = lane & 3;
        if (lane < 40) {
#pragma unroll
            for (int m = 0; m < 8; ++m) wo[m] = Wout[po * HID + kq * 8 + m];
            bo = bout[po];
        } else {
#pragma unroll
            for (int m = 0; m < 8; ++m) wo[m] = 0.f;
        }
        int cL0 = -1, cL1 = -1;
        for (int g = 0; g < NGRP; ++g) {
            if ((g & 3) == 0) {          // one poll pair per super-group
                waitge(&ctr[1], 4 * g + 15, cL0);              // h0 for 16 steps
                // ctr[3] >= 4g-17 covers BOTH xg1 overwrite safety AND the
                // h1 data for proj groups (g-8 .. g-5) in this super-group.
                if (g >= 8) waitge(&ctr[3], 4 * g - 17, cL1);
            }
#pragma unroll
            for (int u = 0; u < 4; ++u) {
                const int t = 4 * g + u;
                LOADH2(&h0r[t & RMASK][16 * gp], hq)
                DOTPK(wi1, hq, q0, q1, q2, q3)
                if (gp == 0) {
                    float4 o;
                    o.x = q0 + b1v[0]; o.y = q1 + b1v[1];
                    o.z = q2 + b1v[2]; o.w = q3 + b1v[3];
                    *(float4*)&xg1[t & RMASK][j][0] = o;
                }
            }
            pub(&ctr[2], 4 * g + 3, lane);
            if (g >= 8) {
                const int gy = g - 8;    // proj lags 8 groups (h1r holds 8 groups)
#pragma unroll
                for (int u = 0; u < 4; ++u) {
                    const int ty = 4 * gy + u;
                    const float* hb = &h1r[ty & RMASK][kq * 8];
                    const float4 va = *(const float4*)hb;
                    const float4 vb = *(const float4*)(hb + 4);
                    float acc = wo[0]*va.x + wo[1]*va.y + wo[2]*va.z + wo[3]*va.w
                              + wo[4]*vb.x + wo[5]*vb.y + wo[6]*vb.z + wo[7]*vb.w;
                    acc += quad<0xB1>(acc);
                    acc += quad<0x4E>(acc);
                    if (lane < 40 && kq == 0) yb[(size_t)ty * OUTD + po] = acc + bo;
                }
                pub(&ctr[4], 4 * gy + 3, lane);
            }
        }
        // tail: proj the last 8 groups
        for (int gy = NGRP - 8; gy < NGRP; ++gy) {
            waitge(&ctr[3], 4 * gy + 3, cL1);
#pragma unroll
            for (int u = 0; u < 4; ++u) {
                const int ty = 4 * gy + u;
                const float* hb = &h1r[ty & RMASK][kq * 8];
                const float4 va = *(const float4*)hb;
                const float4 vb = *(const float4*)(hb + 4);
                float acc = wo[0]*va.x + wo[1]*va.y + wo[2]*va.z + wo[3]*va.w
                          + wo[4]*vb.x + wo[5]*vb.y + wo[6]*vb.z + wo[7]*vb.w;
                acc += quad<0xB1>(acc);
                acc += quad<0x4E>(acc);
                if (lane < 40 && kq == 0) yb[(size_t)ty * OUTD + po] = acc + bo;
            }
            pub(&ctr[4], 4 * gy + 3, lane);
        }
    } else if (role == 2) {
        // ===================== L1 recurrence: steps 4g..4g+3 =====================
        const int j = lane >> 1, gp = lane & 1;
        v2f wh1[4][8];
#pragma unroll
        for (int g = 0; g < 4; ++g) {
            const float* wr = Whh1 + (g * HID + j) * HID + 16 * gp;
#pragma unroll
            for (int m = 0; m < 8; ++m) wh1[g][m] = (v2f){wr[2*m], wr[2*m + 1]};
        }
        float c1 = 0.f;
        int cQd = -1, cPrj = -1;
        __builtin_amdgcn_s_setprio(1);   // chain wave
        for (int g = 0; g < NGRP; ++g) {
            if ((g & 3) == 0) {
                waitge(&ctr[2], 4 * g + 15, cQd);              // xg1 for 16 steps
                if (g >= 8) waitge(&ctr[4], 4 * g - 17, cPrj); // h1 ring slots free
            }
#pragma unroll
            for (int u = 0; u < 4; ++u) {
                const int t = 4 * g + u;
                LOADH2(&h1r[(t + RMASK) & RMASK][16 * gp], hv)
                DOTPK(wh1, hv, s0, s1, s2, s3)
                const float4 xg = *(const float4*)&xg1[t & RMASK][j][0];
                const float hval = gate_act(s0 + xg.x, s1 + xg.y,
                                            s2 + xg.z, s3 + xg.w, gp, c1);
                if (gp == 0) h1r[t & RMASK][j] = hval;
            }
            pub(&ctr[3], 4 * g + 3, lane);
        }
    } else {
        // ============ producer: xg0[4g..4g+3] = Wih0*x + b0; x staging ============
        // lane owns 2 gate-rows: (gA=lane>>5, jj) and (gB=gA+2, jj).
        const int jj = lane & 31;
        const int gA = lane >> 5;        // 0..1
        const int gB = 2 + (lane >> 5);  // 2..3

        v2f wa2[24], wb2[24];
        float wa48, wb48, b0a, b0b;
        {
            const float* wra = Wih0 + (gA * HID + jj) * NIN;
            const float* wrb = Wih0 + (gB * HID + jj) * NIN;
#pragma unroll
            for (int m = 0; m < 24; ++m) {
                wa2[m] = (v2f){wra[2*m], wra[2*m + 1]};
                wb2[m] = (v2f){wrb[2*m], wrb[2*m + 1]};
            }
            wa48 = wra[48]; wb48 = wrb[48];
            b0a = bih0[gA * HID + jj] + bhh0[gA * HID + jj];
            b0b = bih0[gB * HID + jj] + bhh0[gB * HID + jj];
        }

        int laddr[13];
#pragma unroll
        for (int r = 0; r < 13; ++r) {
            const int idx = lane + r * 64;
            const int s_  = idx / NIN;
            laddr[r] = s_ * XSTR + (idx - s_ * NIN);
        }
        float xr[13];

        auto issue = [&](int cn) {
            const float* src = xb + (size_t)cn * 16 * NIN;
#pragma unroll
            for (int r = 0; r < 12; ++r) xr[r] = src[lane + r * 64];
            if (lane < 16) xr[12] = src[lane + 768];
        };
        auto drain = [&](int cn) {
            float* dst = &xs[(cn & 1) * (16 * XSTR)];
#pragma unroll
            for (int r = 0; r < 12; ++r) dst[laddr[r]] = xr[r];
            if (lane < 16) dst[laddr[12]] = xr[12];
        };
        auto pdot = [&](int t) {
            const float* xp = &xs[((t >> 4) & 1) * (16 * XSTR) + (t & 15) * XSTR];
            const float4* x4 = (const float4*)xp;   // wave-uniform broadcast reads
            v2f aA0 = (v2f){b0a, 0.f}, aA1 = (v2f){0.f, 0.f};
            v2f aB0 = (v2f){b0b, 0.f}, aB1 = (v2f){0.f, 0.f};
#pragma unroll
            for (int u = 0; u < 12; ++u) {
                const float4 xv = x4[u];
                const v2f xlo = (v2f){xv.x, xv.y};
                const v2f xhi = (v2f){xv.z, xv.w};
                pkfma(aA0, wa2[2*u],     xlo);
                pkfma(aA1, wa2[2*u + 1], xhi);
                pkfma(aB0, wb2[2*u],     xlo);
                pkfma(aB1, wb2[2*u + 1], xhi);
            }
            const float x48 = xp[48];
            const float a0 = fmaf(wa48, x48, (aA0.x + aA0.y) + (aA1.x + aA1.y));
            const float a2 = fmaf(wb48, x48, (aB0.x + aB0.y) + (aB1.x + aB1.y));
            xg0[t & RMASK][jj][gA] = a0;
            xg0[t & RMASK][jj][gB] = a2;
        };

        // prologue: stage chunk 0 (xs is producer-private; in-wave lgkmcnt orders it)
        issue(0);
        drain(0);

        int cL0 = -1;
        for (int g = 0; g < NGRP; ++g) {
            if ((g & 3) == 0 && g >= 8)
                waitge(&ctr[1], 4 * g - 17, cL0);   // xg0 ring slots free (16 steps)
            const int cn = (g >> 2) + 1;
            if ((g & 3) == 0 && cn < 64) issue(cn);
            pdot(4 * g); pdot(4 * g + 1); pdot(4 * g + 2); pdot(4 * g + 3);
            if ((g & 3) == 2 && cn < 64) drain(cn);
            pub(&ctr[0], 4 * g + 3, lane);
        }
    }
}

extern "C" void kernel_launch(void* const* d_in, const int* in_sizes, int n_in,
                              void* d_out, int out_size, void* d_ws, size_t ws_size,
                              hipStream_t stream) {
    (void)in_sizes; (void)n_in; (void)d_ws; (void)ws_size; (void)out_size;
    const float* x    = (const float*)d_in[0];
    const float* Wih0 = (const float*)d_in[1];
    const float* Whh0 = (const float*)d_in[2];
    const float* bih0 = (const float*)d_in[3];
    const float* bhh0 = (const float*)d_in[4];
    const float* Wih1 = (const float*)d_in[5];
    const float* Whh1 = (const float*)d_in[6];
    const float* bih1 = (const float*)d_in[7];
    const float* bhh1 = (const float*)d_in[8];
    const float* Wout = (const float*)d_in[9];
    const float* bout = (const float*)d_in[10];
    float* y = (float*)d_out;

    lstm_amort<<<dim3(512), dim3(256), 0, stream>>>(
        x, Wih0, Whh0, bih0, bhh0, Wih1, Whh1, bih1, bhh1, Wout, bout, y);
}